// Round 1
// baseline (1465.227 us; speedup 1.0000x reference)
//
#include <hip/hip_runtime.h>

// CoStGcnBlock fp32 baseline.
// Pipeline: K0 prep -> K1 graphconv(+bn1 stats) -> K2 finalize bn1 ->
//           K3 temporal conv(+bn2 stats, reads h_pre & x, recomputes hn on the fly)
//           -> K2 finalize bn2 -> K5 bn2-apply + residual + relu (in-place on d_out).

#define EPSV 1e-5f

// problem constants
#define TVN 7500       // T*V
#define NTVf 480000.0f // N*T*V (per-channel count)
#define TOTE 30720000  // N*C*T*V

// ws float offsets
#define HPRE_OFF 0
#define AE_OFF   30720000   // 1875
#define W2T_OFF  30721920   // 12288  [s][c][o]
#define WTT_OFF  30734208   // 36864  [kt][c][o]
#define BSUM_OFF 30771072   // 64
#define SCSH_OFF 30771136   // 256: sc1[64] sh1[64] sc2[64] sh2[64]
#define STAT_OFF 30771392   // 256: sum1[64] sq1[64] sum2[64] sq2[64]
// total 30771648 floats = ~123.1 MB of ws

__global__ __launch_bounds__(256) void k0_prep(
    const float* __restrict__ A, const float* __restrict__ attn,
    const float* __restrict__ wg, const float* __restrict__ bg,
    const float* __restrict__ wt, float* __restrict__ ws) {
  int i = blockIdx.x * 256 + threadIdx.x;
  int stride = gridDim.x * 256;
  for (int j = i; j < 1875; j += stride) ws[AE_OFF + j] = A[j] * attn[j];
  for (int j = i; j < 12288; j += stride) {       // W2T[s][c][o] = wg[s][o][c]
    int s = j >> 12, r = j & 4095, c = r >> 6, o = r & 63;
    ws[W2T_OFF + j] = wg[(s << 12) + (o << 6) + c];
  }
  for (int j = i; j < 36864; j += stride) {       // wtT[kt][c][o] = wt[o][c][kt]
    int kt = j >> 12, r = j & 4095, c = r >> 6, o = r & 63;
    ws[WTT_OFF + j] = wt[((o << 6) + c) * 9 + kt];
  }
  for (int j = i; j < 64; j += stride)
    ws[BSUM_OFF + j] = bg[j] + bg[64 + j] + bg[128 + j];
  for (int j = i; j < 256; j += stride) ws[STAT_OFF + j] = 0.f;  // ws is poisoned each launch
}

// K1: h_pre[n,o,col] = sum_s sum_c wg[s,o,c] * (sum_v x[n,c,t,v]*Ae[s,v,w]) + bsum[o]
// block: (t-tile of 4 => 100 cols) x n. 512 threads.
__global__ __launch_bounds__(512) void k1_gcn(
    const float* __restrict__ x, const float* __restrict__ Ae,
    const float* __restrict__ W2T, const float* __restrict__ bsum,
    float* __restrict__ hpre, float* __restrict__ stat1) {
  const int tb = blockIdx.x;          // 0..74
  const int n = blockIdx.y;           // 0..63
  const int tid = threadIdx.x;
  __shared__ float xs[64 * 101];      // x tile [c][100], stride 101 (conflict-free col reads)
  __shared__ float xa[64 * 100];      // xa_s [c][100]
  __shared__ float ps[64 * 26];
  __shared__ float pq[64 * 26];
  const int colbase = tb * 100;

  // stage x tile (float4 chunks)
  for (int ch = tid; ch < 1600; ch += 512) {
    int c = ch / 25, q = (ch % 25) * 4;
    const float4 v4 = *(const float4*)(x + (n * 64 + c) * TVN + colbase + q);
    int b = c * 101 + q;
    xs[b] = v4.x; xs[b + 1] = v4.y; xs[b + 2] = v4.z; xs[b + 3] = v4.w;
  }

  const int og = tid & 15, cg = tid >> 4;     // stage-B mapping: o0=og*4, col0=cg*4
  const int o0 = og * 4, col0 = cg * 4;
  float acc[4][4];
#pragma unroll
  for (int i = 0; i < 4; ++i)
#pragma unroll
    for (int j = 0; j < 4; ++j) acc[i][j] = 0.f;

  for (int s = 0; s < 3; ++s) {
    __syncthreads();   // xs staged (s=0) / previous stage-B done reading xa
    if (tid < 256) {   // stage A: xa[c][tt*25+w] = sum_v xs[c][tt*25+v]*Ae[s][v][w]
      const int c = tid & 63, tt = tid >> 6;
      float aw[25];
#pragma unroll
      for (int w = 0; w < 25; ++w) aw[w] = 0.f;
#pragma unroll
      for (int v = 0; v < 25; ++v) {
        const float xv = xs[c * 101 + tt * 25 + v];     // per-lane, stride 101: conflict-free
#pragma unroll
        for (int w = 0; w < 25; ++w)
          aw[w] += xv * Ae[(s * 25 + v) * 25 + w];      // wave-uniform -> s_load from L2
      }
#pragma unroll
      for (int w = 0; w < 25; ++w) xa[c * 100 + tt * 25 + w] = aw[w];
    }
    __syncthreads();
    if (cg < 25) {     // stage B: 4x4 register tile GEMM, K=64 per s
#pragma unroll 4
      for (int c = 0; c < 64; ++c) {
        const float4 a4 = *(const float4*)(W2T + (s * 64 + c) * 64 + o0);  // L2-hot
        const float4 b4 = *(const float4*)(&xa[c * 100 + col0]);
        acc[0][0] += a4.x * b4.x; acc[0][1] += a4.x * b4.y; acc[0][2] += a4.x * b4.z; acc[0][3] += a4.x * b4.w;
        acc[1][0] += a4.y * b4.x; acc[1][1] += a4.y * b4.y; acc[1][2] += a4.y * b4.z; acc[1][3] += a4.y * b4.w;
        acc[2][0] += a4.z * b4.x; acc[2][1] += a4.z * b4.y; acc[2][2] += a4.z * b4.z; acc[2][3] += a4.z * b4.w;
        acc[3][0] += a4.w * b4.x; acc[3][1] += a4.w * b4.y; acc[3][2] += a4.w * b4.z; acc[3][3] += a4.w * b4.w;
      }
    }
  }

  if (cg < 25) {       // epilogue: bias, store h_pre, bn1 partial stats
#pragma unroll
    for (int i = 0; i < 4; ++i) {
      const float bo = bsum[o0 + i];
      float4 v;
      v.x = acc[i][0] + bo; v.y = acc[i][1] + bo; v.z = acc[i][2] + bo; v.w = acc[i][3] + bo;
      *(float4*)(hpre + (n * 64 + o0 + i) * TVN + colbase + col0) = v;
      ps[(o0 + i) * 26 + cg] = v.x + v.y + v.z + v.w;
      pq[(o0 + i) * 26 + cg] = v.x * v.x + v.y * v.y + v.z * v.z + v.w * v.w;
    }
  }
  __syncthreads();
  if (tid < 64) {
    float s1 = 0.f, q1 = 0.f;
    for (int g = 0; g < 25; ++g) { s1 += ps[tid * 26 + g]; q1 += pq[tid * 26 + g]; }
    atomicAdd(stat1 + tid, s1);
    atomicAdd(stat1 + 64 + tid, q1);
  }
}

// K2: finalize BN params: scale = gamma*rsqrt(var+eps), shift = beta - mean*scale
__global__ __launch_bounds__(64) void k2_fin(
    const float* __restrict__ gamma, const float* __restrict__ beta,
    const float* __restrict__ stat, float* __restrict__ scsh) {
  const int o = threadIdx.x;
  double s = (double)stat[o], q = (double)stat[64 + o];
  double mean = s / (double)NTVf;
  double var = q / (double)NTVf - mean * mean;
  float sc = (float)((double)gamma[o] / sqrt(var + (double)EPSV));
  scsh[o] = sc;
  scsh[64 + o] = beta[o] - (float)mean * sc;
}

// K3: temporal conv (9,1). hn = relu(bn1(h_pre)+x) recomputed into LDS with +-4t halo,
// C processed in two 32-row halves. Writes y_pre(+bt) to d_out, accumulates bn2 stats.
// block: 200 output cols x n. 832 threads (16 og x 52 cg; 50 cg active).
__global__ __launch_bounds__(832) void k3_conv(
    const float* __restrict__ x, const float* __restrict__ hpre,
    const float* __restrict__ wtT, const float* __restrict__ bt,
    const float* __restrict__ scsh1, float* __restrict__ out,
    float* __restrict__ stat2) {
  const int wb = blockIdx.x;          // 0..37 (last block partial)
  const int n = blockIdx.y;
  const int tid = threadIdx.x;
  __shared__ float hnb[32 * 400];     // half-C staged hn tile [c_local][400]
  __shared__ float wtl[32 * 64];      // wt panel [c_local][o]
  const int og = tid & 15, cg = tid >> 4;
  const int o0 = og * 4, col0 = cg * 4;
  const int outbase = wb * 200;
  const bool act = (cg < 50) && (outbase + col0 < TVN);
  float acc[4][4];
#pragma unroll
  for (int i = 0; i < 4; ++i)
#pragma unroll
    for (int j = 0; j < 4; ++j) acc[i][j] = 0.f;

  for (int ch = 0; ch < 2; ++ch) {
    __syncthreads();   // previous half's compute done before hnb overwrite
    for (int u = tid; u < 3200; u += 832) {     // stage hn half: 32 rows x 400 cols
      const int cl = u / 100;
      const int c = ch * 32 + cl;
      const int q = (u % 100) * 4;
      const int gc = outbase - 100 + q;         // global col, 16B aligned
      float4 r;
      if (gc >= 0 && gc < TVN) {
        const float4 h4 = *(const float4*)(hpre + (n * 64 + c) * TVN + gc);
        const float4 x4 = *(const float4*)(x + (n * 64 + c) * TVN + gc);
        const float sc = scsh1[c], sh = scsh1[64 + c];
        r.x = fmaxf(fmaf(h4.x, sc, sh) + x4.x, 0.f);
        r.y = fmaxf(fmaf(h4.y, sc, sh) + x4.y, 0.f);
        r.z = fmaxf(fmaf(h4.z, sc, sh) + x4.z, 0.f);
        r.w = fmaxf(fmaf(h4.w, sc, sh) + x4.w, 0.f);
      } else {
        r.x = 0.f; r.y = 0.f; r.z = 0.f; r.w = 0.f;   // conv zero-padding
      }
      *(float4*)&hnb[cl * 400 + q] = r;
    }
    for (int kt = 0; kt < 9; ++kt) {
      __syncthreads();  // previous kt done reading wtl (and hnb staged at kt=0)
      for (int u = tid; u < 2048; u += 832)
        wtl[u] = wtT[kt * 4096 + ch * 2048 + u];
      __syncthreads();
      if (act) {
        const int bofs = col0 + kt * 25;        // staged col of this tap
#pragma unroll 4
        for (int c = 0; c < 32; ++c) {
          const float4 a4 = *(const float4*)&wtl[c * 64 + o0];
          const float b0 = hnb[c * 400 + bofs];
          const float b1 = hnb[c * 400 + bofs + 1];
          const float b2 = hnb[c * 400 + bofs + 2];
          const float b3 = hnb[c * 400 + bofs + 3];
          acc[0][0] += a4.x * b0; acc[0][1] += a4.x * b1; acc[0][2] += a4.x * b2; acc[0][3] += a4.x * b3;
          acc[1][0] += a4.y * b0; acc[1][1] += a4.y * b1; acc[1][2] += a4.y * b2; acc[1][3] += a4.y * b3;
          acc[2][0] += a4.z * b0; acc[2][1] += a4.z * b1; acc[2][2] += a4.z * b2; acc[2][3] += a4.z * b3;
          acc[3][0] += a4.w * b0; acc[3][1] += a4.w * b1; acc[3][2] += a4.w * b2; acc[3][3] += a4.w * b3;
        }
      }
    }
  }

  __syncthreads();                // compute done; reuse hnb for stats partials
  float* psb = hnb;               // [64][51]
  float* pqb = hnb + 64 * 51;
  if (cg < 50) {
#pragma unroll
    for (int i = 0; i < 4; ++i) {
      float ssum = 0.f, sq = 0.f;
      if (act) {
        const float bo = bt[o0 + i];
        float4 v;
        v.x = acc[i][0] + bo; v.y = acc[i][1] + bo; v.z = acc[i][2] + bo; v.w = acc[i][3] + bo;
        *(float4*)(out + (n * 64 + o0 + i) * TVN + outbase + col0) = v;
        ssum = v.x + v.y + v.z + v.w;
        sq = v.x * v.x + v.y * v.y + v.z * v.z + v.w * v.w;
      }
      psb[(o0 + i) * 51 + cg] = ssum;
      pqb[(o0 + i) * 51 + cg] = sq;
    }
  }
  __syncthreads();
  if (tid < 64) {
    float s2 = 0.f, q2 = 0.f;
    for (int g = 0; g < 50; ++g) { s2 += psb[tid * 51 + g]; q2 += pqb[tid * 51 + g]; }
    atomicAdd(stat2 + tid, s2);
    atomicAdd(stat2 + 64 + tid, q2);
  }
}

// K5: out = relu(bn2(y_pre) + x), in-place on d_out
__global__ __launch_bounds__(256) void k5_final(
    const float* __restrict__ x, const float* __restrict__ scsh2,
    float* __restrict__ out) {
  const int total = TOTE / 4;
  for (int ch = blockIdx.x * 256 + threadIdx.x; ch < total; ch += gridDim.x * 256) {
    const int f = ch * 4;
    const int o = (f / TVN) & 63;
    const float sc = scsh2[o], sh = scsh2[64 + o];
    float4 y4 = *(float4*)(out + f);
    const float4 x4 = *(const float4*)(x + f);
    y4.x = fmaxf(fmaf(y4.x, sc, sh) + x4.x, 0.f);
    y4.y = fmaxf(fmaf(y4.y, sc, sh) + x4.y, 0.f);
    y4.z = fmaxf(fmaf(y4.z, sc, sh) + x4.z, 0.f);
    y4.w = fmaxf(fmaf(y4.w, sc, sh) + x4.w, 0.f);
    *(float4*)(out + f) = y4;
  }
}

extern "C" void kernel_launch(void* const* d_in, const int* in_sizes, int n_in,
                              void* d_out, int out_size, void* d_ws, size_t ws_size,
                              hipStream_t stream) {
  const float* x      = (const float*)d_in[0];
  const float* A      = (const float*)d_in[1];
  const float* attn   = (const float*)d_in[2];
  const float* wg     = (const float*)d_in[3];
  const float* bg     = (const float*)d_in[4];
  const float* gamma1 = (const float*)d_in[5];
  const float* beta1  = (const float*)d_in[6];
  const float* wt     = (const float*)d_in[7];
  const float* bt     = (const float*)d_in[8];
  const float* gamma2 = (const float*)d_in[9];
  const float* beta2  = (const float*)d_in[10];
  float* ws = (float*)d_ws;
  float* out = (float*)d_out;

  k0_prep<<<64, 256, 0, stream>>>(A, attn, wg, bg, wt, ws);
  k1_gcn<<<dim3(75, 64), 512, 0, stream>>>(
      x, ws + AE_OFF, ws + W2T_OFF, ws + BSUM_OFF, ws + HPRE_OFF, ws + STAT_OFF);
  k2_fin<<<1, 64, 0, stream>>>(gamma1, beta1, ws + STAT_OFF, ws + SCSH_OFF);
  k3_conv<<<dim3(38, 64), 832, 0, stream>>>(
      x, ws + HPRE_OFF, ws + WTT_OFF, bt, ws + SCSH_OFF, out, ws + STAT_OFF + 128);
  k2_fin<<<1, 64, 0, stream>>>(gamma2, beta2, ws + STAT_OFF + 128, ws + SCSH_OFF + 128);
  k5_final<<<2048, 256, 0, stream>>>(x, ws + SCSH_OFF + 128, out);
}

// Round 3
// 854.706 us; speedup vs baseline: 1.7143x; 1.7143x over previous
//
#include <hip/hip_runtime.h>

// CoStGcnBlock. K3 rewritten as split-bf16 MFMA (3-product emulation of fp32).
// Pipeline: K0 prep -> K1 graphconv fp32 (+bn1 stats) -> K2 finalize bn1 ->
//           K3 temporal conv MFMA (+bn2 stats) -> K2 finalize bn2 -> K5 final.

#define EPSV 1e-5f
#define TVN 7500       // T*V
#define NTVf 480000.0f // N*T*V
#define TOTE 30720000  // N*C*T*V

// ws float offsets
#define HPRE_OFF 0
#define AE_OFF   30720000   // 1875
#define W2T_OFF  30721920   // 12288  [s][c][o] fp32 (K1)
#define WTT_OFF  30734208   // 36864 floats reused as 2x 36864 bf16: wAh|wAl [kt][ch][o][c32]
#define BSUM_OFF 30771072   // 64
#define SCSH_OFF 30771136   // 256
#define STAT_OFF 30771392   // 256

typedef __attribute__((ext_vector_type(8))) short short8v;
typedef __attribute__((ext_vector_type(4))) float f32x4;

__device__ __forceinline__ unsigned short f2bf(float f) {
  unsigned u = __float_as_uint(f);
  u += 0x7fffu + ((u >> 16) & 1u);
  return (unsigned short)(u >> 16);
}

__global__ __launch_bounds__(256) void k0_prep(
    const float* __restrict__ A, const float* __restrict__ attn,
    const float* __restrict__ wg, const float* __restrict__ bg,
    const float* __restrict__ wt, float* __restrict__ ws) {
  int i = blockIdx.x * 256 + threadIdx.x;
  int stride = gridDim.x * 256;
  for (int j = i; j < 1875; j += stride) ws[AE_OFF + j] = A[j] * attn[j];
  for (int j = i; j < 12288; j += stride) {       // W2T[s][c][o] = wg[s][o][c]
    int s = j >> 12, r = j & 4095, c = r >> 6, o = r & 63;
    ws[W2T_OFF + j] = wg[(s << 12) + (o << 6) + c];
  }
  // split-bf16 temporal weights: wAh/wAl [kt][ch][o][c32]
  unsigned short* wA16 = (unsigned short*)(ws + WTT_OFF);
  for (int j = i; j < 36864; j += stride) {
    int c = j & 31, o = (j >> 5) & 63, chkt = j >> 11;
    int ch = chkt & 1, kt = chkt >> 1;
    float f = wt[((o << 6) + (ch << 5) + c) * 9 + kt];
    unsigned short hi = f2bf(f);
    float lo = f - __uint_as_float((unsigned)hi << 16);
    wA16[j] = hi;
    wA16[36864 + j] = f2bf(lo);
  }
  for (int j = i; j < 64; j += stride)
    ws[BSUM_OFF + j] = bg[j] + bg[64 + j] + bg[128 + j];
  for (int j = i; j < 256; j += stride) ws[STAT_OFF + j] = 0.f;
}

// K1: fp32 graph conv (unchanged from passing baseline)
__global__ __launch_bounds__(512) void k1_gcn(
    const float* __restrict__ x, const float* __restrict__ Ae,
    const float* __restrict__ W2T, const float* __restrict__ bsum,
    float* __restrict__ hpre, float* __restrict__ stat1) {
  const int tb = blockIdx.x;
  const int n = blockIdx.y;
  const int tid = threadIdx.x;
  __shared__ float xs[64 * 101];
  __shared__ float xa[64 * 100];
  __shared__ float ps[64 * 26];
  __shared__ float pq[64 * 26];
  const int colbase = tb * 100;

  for (int ch = tid; ch < 1600; ch += 512) {
    int c = ch / 25, qd = (ch % 25) * 4;
    const float4 v4 = *(const float4*)(x + (n * 64 + c) * TVN + colbase + qd);
    int b = c * 101 + qd;
    xs[b] = v4.x; xs[b + 1] = v4.y; xs[b + 2] = v4.z; xs[b + 3] = v4.w;
  }

  const int og = tid & 15, cg = tid >> 4;
  const int o0 = og * 4, col0 = cg * 4;
  float acc[4][4];
#pragma unroll
  for (int i = 0; i < 4; ++i)
#pragma unroll
    for (int j = 0; j < 4; ++j) acc[i][j] = 0.f;

  for (int s = 0; s < 3; ++s) {
    __syncthreads();
    if (tid < 256) {
      const int c = tid & 63, tt = tid >> 6;
      float aw[25];
#pragma unroll
      for (int w = 0; w < 25; ++w) aw[w] = 0.f;
#pragma unroll
      for (int v = 0; v < 25; ++v) {
        const float xv = xs[c * 101 + tt * 25 + v];
#pragma unroll
        for (int w = 0; w < 25; ++w)
          aw[w] += xv * Ae[(s * 25 + v) * 25 + w];
      }
#pragma unroll
      for (int w = 0; w < 25; ++w) xa[c * 100 + tt * 25 + w] = aw[w];
    }
    __syncthreads();
    if (cg < 25) {
#pragma unroll 4
      for (int c = 0; c < 64; ++c) {
        const float4 a4 = *(const float4*)(W2T + (s * 64 + c) * 64 + o0);
        const float4 b4 = *(const float4*)(&xa[c * 100 + col0]);
        acc[0][0] += a4.x * b4.x; acc[0][1] += a4.x * b4.y; acc[0][2] += a4.x * b4.z; acc[0][3] += a4.x * b4.w;
        acc[1][0] += a4.y * b4.x; acc[1][1] += a4.y * b4.y; acc[1][2] += a4.y * b4.z; acc[1][3] += a4.y * b4.w;
        acc[2][0] += a4.z * b4.x; acc[2][1] += a4.z * b4.y; acc[2][2] += a4.z * b4.z; acc[2][3] += a4.z * b4.w;
        acc[3][0] += a4.w * b4.x; acc[3][1] += a4.w * b4.y; acc[3][2] += a4.w * b4.z; acc[3][3] += a4.w * b4.w;
      }
    }
  }

  if (cg < 25) {
#pragma unroll
    for (int i = 0; i < 4; ++i) {
      const float bo = bsum[o0 + i];
      float4 v;
      v.x = acc[i][0] + bo; v.y = acc[i][1] + bo; v.z = acc[i][2] + bo; v.w = acc[i][3] + bo;
      *(float4*)(hpre + (n * 64 + o0 + i) * TVN + colbase + col0) = v;
      ps[(o0 + i) * 26 + cg] = v.x + v.y + v.z + v.w;
      pq[(o0 + i) * 26 + cg] = v.x * v.x + v.y * v.y + v.z * v.z + v.w * v.w;
    }
  }
  __syncthreads();
  if (tid < 64) {
    float s1 = 0.f, q1 = 0.f;
    for (int g = 0; g < 25; ++g) { s1 += ps[tid * 26 + g]; q1 += pq[tid * 26 + g]; }
    atomicAdd(stat1 + tid, s1);
    atomicAdd(stat1 + 64 + tid, q1);
  }
}

__global__ __launch_bounds__(64) void k2_fin(
    const float* __restrict__ gamma, const float* __restrict__ beta,
    const float* __restrict__ stat, float* __restrict__ scsh) {
  const int o = threadIdx.x;
  double s = (double)stat[o], q = (double)stat[64 + o];
  double mean = s / (double)NTVf;
  double var = q / (double)NTVf - mean * mean;
  float sc = (float)((double)gamma[o] / sqrt(var + (double)EPSV));
  scsh[o] = sc;
  scsh[64 + o] = beta[o] - (float)mean * sc;
}

// K3 MFMA: block = 192 output cols x n, 256 threads (4 waves).
// hn recomputed+split into LDS [col 392][c 40(pad)] bf16 hi/lo, per 32-c half.
// Per wave: 4 m-tiles x 3 n-tiles, K=32 per (kt,half), 3-MFMA split emulation.
__global__ __launch_bounds__(256) void k3_conv(
    const float* __restrict__ x, const float* __restrict__ hpre,
    const unsigned short* __restrict__ wAh, const unsigned short* __restrict__ wAl,
    const float* __restrict__ bt, const float* __restrict__ scsh1,
    float* __restrict__ out, float* __restrict__ stat2) {
  const int cb = blockIdx.x;          // 0..39
  const int n = blockIdx.y;
  const int tid = threadIdx.x;
  const int lane = tid & 63, w = tid >> 6;
  const int l15 = lane & 15, q = lane >> 4;
  const int kb8 = q * 8;
  const int outbase = cb * 192;

  __shared__ __align__(16) short smem[2 * 392 * 40];  // hh | hl (62720 B)
  short* hh = smem;
  short* hl = smem + 392 * 40;

  f32x4 acc[4][3];
#pragma unroll
  for (int m = 0; m < 4; ++m)
#pragma unroll
    for (int nt = 0; nt < 3; ++nt) {
      f32x4 z = {0.f, 0.f, 0.f, 0.f};
      acc[m][nt] = z;
    }

  for (int ch = 0; ch < 2; ++ch) {
    __syncthreads();   // previous half's fragment reads done
    // stage: 392 cols x 32 c (c-quad per thread, b64 LDS writes)
    for (int u = tid; u < 3136; u += 256) {
      const int s = u % 392, cq = u / 392;
      const int gc = outbase - 100 + s;
      const int cbase = ch * 32 + cq * 4;
      short4 vh, vl;
      if (gc >= 0 && gc < TVN) {
#pragma unroll
        for (int i = 0; i < 4; ++i) {
          const int c = cbase + i;
          const float h = hpre[(n * 64 + c) * TVN + gc];
          const float xv = x[(n * 64 + c) * TVN + gc];
          const float r = fmaxf(fmaf(h, scsh1[c], scsh1[64 + c]) + xv, 0.f);
          const unsigned short hi = f2bf(r);
          const float lo = r - __uint_as_float((unsigned)hi << 16);
          ((unsigned short*)&vh)[i] = hi;
          ((unsigned short*)&vl)[i] = f2bf(lo);
        }
      } else {
        vh.x = 0; vh.y = 0; vh.z = 0; vh.w = 0;
        vl.x = 0; vl.y = 0; vl.z = 0; vl.w = 0;
      }
      *(short4*)(hh + s * 40 + cq * 4) = vh;
      *(short4*)(hl + s * 40 + cq * 4) = vl;
    }
    __syncthreads();   // staging visible

#pragma unroll 3
    for (int kt = 0; kt < 9; ++kt) {
      short8v ah[4], al[4], bh[3], bl[3];
      const int abase = (kt * 2 + ch) * 2048;
#pragma unroll
      for (int m = 0; m < 4; ++m) {
        const int aoff = abase + (m * 16 + l15) * 32 + kb8;
        ah[m] = *(const short8v*)(wAh + aoff);
        al[m] = *(const short8v*)(wAl + aoff);
      }
#pragma unroll
      for (int nt = 0; nt < 3; ++nt) {
        const int s = w * 48 + nt * 16 + l15 + kt * 25;
        const int boff = s * 40 + kb8;
        bh[nt] = *(const short8v*)(hh + boff);
        bl[nt] = *(const short8v*)(hl + boff);
      }
#pragma unroll
      for (int m = 0; m < 4; ++m)
#pragma unroll
        for (int nt = 0; nt < 3; ++nt) {
          acc[m][nt] = __builtin_amdgcn_mfma_f32_16x16x32_bf16(ah[m], bh[nt], acc[m][nt], 0, 0, 0);
          acc[m][nt] = __builtin_amdgcn_mfma_f32_16x16x32_bf16(ah[m], bl[nt], acc[m][nt], 0, 0, 0);
          acc[m][nt] = __builtin_amdgcn_mfma_f32_16x16x32_bf16(al[m], bh[nt], acc[m][nt], 0, 0, 0);
        }
    }
  }

  // epilogue: bias, store, bn2 partial stats via LDS (alias smem)
  __syncthreads();
  float* ps = (float*)smem;            // [64][65]
  float* pq = ps + 64 * 65;
  const int g = w * 16 + l15;
#pragma unroll
  for (int m = 0; m < 4; ++m)
#pragma unroll
    for (int r = 0; r < 4; ++r) {
      const int o = m * 16 + q * 4 + r;
      const float bo = bt[o];
      float ssum = 0.f, ssq = 0.f;
#pragma unroll
      for (int nt = 0; nt < 3; ++nt) {
        const int col = outbase + (w * 3 + nt) * 16 + l15;
        if (col < TVN) {
          const float v = acc[m][nt][r] + bo;
          out[(n * 64 + o) * TVN + col] = v;
          ssum += v; ssq += v * v;
        }
      }
      ps[o * 65 + g] = ssum;
      pq[o * 65 + g] = ssq;
    }
  __syncthreads();
  if (tid < 64) {
    float s2 = 0.f, q2 = 0.f;
    for (int gg = 0; gg < 64; ++gg) { s2 += ps[tid * 65 + gg]; q2 += pq[tid * 65 + gg]; }
    atomicAdd(stat2 + tid, s2);
    atomicAdd(stat2 + 64 + tid, q2);
  }
}

__global__ __launch_bounds__(256) void k5_final(
    const float* __restrict__ x, const float* __restrict__ scsh2,
    float* __restrict__ out) {
  const int total = TOTE / 4;
  for (int ch = blockIdx.x * 256 + threadIdx.x; ch < total; ch += gridDim.x * 256) {
    const int f = ch * 4;
    const int o = (f / TVN) & 63;
    const float sc = scsh2[o], sh = scsh2[64 + o];
    float4 y4 = *(float4*)(out + f);
    const float4 x4 = *(const float4*)(x + f);
    y4.x = fmaxf(fmaf(y4.x, sc, sh) + x4.x, 0.f);
    y4.y = fmaxf(fmaf(y4.y, sc, sh) + x4.y, 0.f);
    y4.z = fmaxf(fmaf(y4.z, sc, sh) + x4.z, 0.f);
    y4.w = fmaxf(fmaf(y4.w, sc, sh) + x4.w, 0.f);
    *(float4*)(out + f) = y4;
  }
}

extern "C" void kernel_launch(void* const* d_in, const int* in_sizes, int n_in,
                              void* d_out, int out_size, void* d_ws, size_t ws_size,
                              hipStream_t stream) {
  const float* x      = (const float*)d_in[0];
  const float* A      = (const float*)d_in[1];
  const float* attn   = (const float*)d_in[2];
  const float* wg     = (const float*)d_in[3];
  const float* bg     = (const float*)d_in[4];
  const float* gamma1 = (const float*)d_in[5];
  const float* beta1  = (const float*)d_in[6];
  const float* wt     = (const float*)d_in[7];
  const float* bt     = (const float*)d_in[8];
  const float* gamma2 = (const float*)d_in[9];
  const float* beta2  = (const float*)d_in[10];
  float* ws = (float*)d_ws;
  float* out = (float*)d_out;
  const unsigned short* wAh = (const unsigned short*)(ws + WTT_OFF);
  const unsigned short* wAl = wAh + 36864;

  k0_prep<<<64, 256, 0, stream>>>(A, attn, wg, bg, wt, ws);
  k1_gcn<<<dim3(75, 64), 512, 0, stream>>>(
      x, ws + AE_OFF, ws + W2T_OFF, ws + BSUM_OFF, ws + HPRE_OFF, ws + STAT_OFF);
  k2_fin<<<1, 64, 0, stream>>>(gamma1, beta1, ws + STAT_OFF, ws + SCSH_OFF);
  k3_conv<<<dim3(40, 64), 256, 0, stream>>>(
      x, ws + HPRE_OFF, wAh, wAl, bt, ws + SCSH_OFF, out, ws + STAT_OFF + 128);
  k2_fin<<<1, 64, 0, stream>>>(gamma2, beta2, ws + STAT_OFF + 128, ws + SCSH_OFF + 128);
  k5_final<<<2048, 256, 0, stream>>>(x, ws + SCSH_OFF + 128, out);
}

// Round 6
// 688.080 us; speedup vs baseline: 2.1294x; 1.2422x over previous
//
#include <hip/hip_runtime.h>

// CoStGcnBlock. K1 and K3 both split-bf16 MFMA (3-product emulation of fp32).
// Pipeline: K0 prep -> K1 graphconv MFMA (+bn1 stats) -> K2 finalize bn1 ->
//           K3 temporal conv MFMA (+bn2 stats) -> K2 finalize bn2 -> K5 final.

#define EPSV 1e-5f
#define TVN 7500       // T*V
#define NTVf 480000.0f // N*T*V
#define TOTE 30720000  // N*C*T*V

// ws float offsets
#define HPRE_OFF 0
#define WTT_OFF  30720000   // K3 weights: 2x 36864 bf16 (wAh|wAl), = 36864 floats
#define AEP_OFF  30756864   // AePh[3072]+AePl[3072] shorts = 3072 floats
#define WGP_OFF  30759936   // WgPh[12288]+WgPl[12288] shorts = 12288 floats
#define BSUM_OFF 30772224   // 64
#define SCSH_OFF 30772288   // 256
#define STAT_OFF 30772544   // 256  (end 30772800 floats = 123.1 MB)

typedef __attribute__((ext_vector_type(8))) short short8v;
typedef __attribute__((ext_vector_type(4))) float f32x4;

__device__ __forceinline__ unsigned short f2bf(float f) {
  unsigned u = __float_as_uint(f);
  u += 0x7fffu + ((u >> 16) & 1u);
  return (unsigned short)(u >> 16);
}
__device__ __forceinline__ float bf2f(unsigned short h) {
  return __uint_as_float((unsigned)h << 16);
}

__global__ __launch_bounds__(256) void k0_prep(
    const float* __restrict__ A, const float* __restrict__ attn,
    const float* __restrict__ wg, const float* __restrict__ bg,
    const float* __restrict__ wt, float* __restrict__ ws) {
  int i = blockIdx.x * 256 + threadIdx.x;
  int stride = gridDim.x * 256;
  // K3 split-bf16 temporal weights: wAh/wAl [kt][ch][o][c32]
  unsigned short* wA16 = (unsigned short*)(ws + WTT_OFF);
  for (int j = i; j < 36864; j += stride) {
    int c = j & 31, o = (j >> 5) & 63, chkt = j >> 11;
    int ch = chkt & 1, kt = chkt >> 1;
    float f = wt[((o << 6) + (ch << 5) + c) * 9 + kt];
    unsigned short hi = f2bf(f);
    wA16[j] = hi;
    wA16[36864 + j] = f2bf(f - bf2f(hi));
  }
  // K1 stage-1 B operand: AeT fragments [s][nb][lane][8], zero-padded v>=25 / w>=25
  unsigned short* AePh = (unsigned short*)(ws + AEP_OFF);
  unsigned short* AePl = AePh + 3072;
  for (int j = i; j < 3072; j += stride) {
    int e = j & 7, l = (j >> 3) & 63, nb = (j >> 9) & 1, s = j >> 10;
    int v = (l >> 4) * 8 + e, wv = nb * 16 + (l & 15);
    float val = (v < 25 && wv < 25) ? A[(s * 25 + v) * 25 + wv] * attn[(s * 25 + v) * 25 + wv] : 0.f;
    unsigned short hi = f2bf(val);
    AePh[j] = hi;
    AePl[j] = f2bf(val - bf2f(hi));
  }
  // K1 stage-2 A operand: wg fragments [s][mt][ks][lane][8]
  unsigned short* WgPh = (unsigned short*)(ws + WGP_OFF);
  unsigned short* WgPl = WgPh + 12288;
  for (int j = i; j < 12288; j += stride) {
    int e = j & 7, l = (j >> 3) & 63, ks = (j >> 9) & 1, mt = (j >> 10) & 3, s = j >> 12;
    int o = mt * 16 + (l & 15), c = ks * 32 + (l >> 4) * 8 + e;
    float val = wg[(s * 64 + o) * 64 + c];
    unsigned short hi = f2bf(val);
    WgPh[j] = hi;
    WgPl[j] = f2bf(val - bf2f(hi));
  }
  for (int j = i; j < 64; j += stride)
    ws[BSUM_OFF + j] = bg[j] + bg[64 + j] + bg[128 + j];
  for (int j = i; j < 256; j += stride) ws[STAT_OFF + j] = 0.f;
}

// K1 MFMA: block = (t-tile of 8 -> 200 cols) x n, 256 threads (4 waves, 2m x 2n).
// Stage1 per s: xa = x @ AeT via MFMA (x A-frags held in regs, K=v pad 32),
//   D1 split to bf16 -> LDS B[col(t,w)][c] (k-pad 72 -> 144B stride).
// Stage2 per s: h += WG_s @ B_s, K=64 (2 k-steps), 13 n-tiles of 16.
__global__ __launch_bounds__(256) void k1_gcn(
    const float* __restrict__ x,
    const unsigned short* __restrict__ AePh, const unsigned short* __restrict__ AePl,
    const unsigned short* __restrict__ WgPh, const unsigned short* __restrict__ WgPl,
    const float* __restrict__ bsum, float* __restrict__ hpre,
    float* __restrict__ stat1) {
  const int tb = blockIdx.x;          // 0..37
  const int n = blockIdx.y;
  const int tid = threadIdx.x;
  const int lane = tid & 63, w = tid >> 6;
  const int l15 = lane & 15, q = lane >> 4;
  const int wm = w & 1, wn = w >> 1;
  const int t0 = tb * 8;

  __shared__ __align__(16) short Bhi[208 * 72];
  __shared__ __align__(16) short Blo[208 * 72];
  __shared__ float ps[128], pq[128];

  // preload x A-frags for this wave's 8 stage-1 m-tiles (held across all 3 s)
  short8v xh[8], xl[8];
#pragma unroll
  for (int i = 0; i < 8; ++i) {
    const int id = w * 8 + i;
    const int tl = id >> 2, cc = id & 3;
    const int c = cc * 16 + l15;
    const int t = t0 + tl;
    const float* base = x + (n * 64 + c) * TVN + t * 25;
    const bool tok = (t < 300);
#pragma unroll
    for (int e = 0; e < 8; ++e) {
      const int v = q * 8 + e;
      const float xv = (tok && v < 25) ? base[v] : 0.f;
      const unsigned short hi = f2bf(xv);
      ((unsigned short*)&xh[i])[e] = hi;
      ((unsigned short*)&xl[i])[e] = f2bf(xv - bf2f(hi));
    }
  }

  f32x4 acc[2][7];
#pragma unroll
  for (int i = 0; i < 2; ++i)
#pragma unroll
    for (int j = 0; j < 7; ++j) {
      f32x4 z = {0.f, 0.f, 0.f, 0.f};
      acc[i][j] = z;
    }

  for (int s = 0; s < 3; ++s) {
    __syncthreads();   // previous s stage-2 done reading B
    // ---- stage 1: compute xa, write split-bf16 into B LDS ----
    short8v aeh[2], ael[2];
#pragma unroll
    for (int nb = 0; nb < 2; ++nb) {
      const int off = ((s * 2 + nb) * 64 + lane) * 8;
      aeh[nb] = *(const short8v*)(AePh + off);
      ael[nb] = *(const short8v*)(AePl + off);
    }
#pragma unroll
    for (int i = 0; i < 8; ++i) {
      const int id = w * 8 + i;
      const int tl = id >> 2, cc = id & 3;
      f32x4 d[2];
#pragma unroll
      for (int nb = 0; nb < 2; ++nb) {
        f32x4 z = {0.f, 0.f, 0.f, 0.f};
        z = __builtin_amdgcn_mfma_f32_16x16x32_bf16(xh[i], aeh[nb], z, 0, 0, 0);
        z = __builtin_amdgcn_mfma_f32_16x16x32_bf16(xh[i], ael[nb], z, 0, 0, 0);
        z = __builtin_amdgcn_mfma_f32_16x16x32_bf16(xl[i], aeh[nb], z, 0, 0, 0);
        d[nb] = z;
      }
      // D1 rows = c = cc*16 + q*4 + r, col w = nb*16+l15 -> B[col2=tl*25+w][k=c]
#pragma unroll
      for (int nb = 0; nb < 2; ++nb) {
        const int wv = nb * 16 + l15;
        if (wv < 25) {
          const int col2 = tl * 25 + wv;
          const int kbase = cc * 16 + q * 4;
          short4 h4, l4;
#pragma unroll
          for (int r = 0; r < 4; ++r) {
            const unsigned short hi = f2bf(d[nb][r]);
            ((unsigned short*)&h4)[r] = hi;
            ((unsigned short*)&l4)[r] = f2bf(d[nb][r] - bf2f(hi));
          }
          *(short4*)(Bhi + col2 * 72 + kbase) = h4;
          *(short4*)(Blo + col2 * 72 + kbase) = l4;
        }
      }
    }
    __syncthreads();   // B_s staged
    // ---- stage 2: h += WG_s @ B_s ----
    short8v wgh[2][2], wgl[2][2];
#pragma unroll
    for (int i = 0; i < 2; ++i) {
      const int mt = wm * 2 + i;
#pragma unroll
      for (int ks = 0; ks < 2; ++ks) {
        const int off = (((s * 4 + mt) * 2 + ks) * 64 + lane) * 8;
        wgh[i][ks] = *(const short8v*)(WgPh + off);
        wgl[i][ks] = *(const short8v*)(WgPl + off);
      }
    }
#pragma unroll
    for (int j = 0; j < 7; ++j) {
      const int tile = wn * 7 + j;
      if (tile < 13) {
#pragma unroll
        for (int ks = 0; ks < 2; ++ks) {
          const int boff = (tile * 16 + l15) * 72 + ks * 32 + q * 8;
          const short8v bh = *(const short8v*)(Bhi + boff);
          const short8v bl = *(const short8v*)(Blo + boff);
#pragma unroll
          for (int i = 0; i < 2; ++i) {
            acc[i][j] = __builtin_amdgcn_mfma_f32_16x16x32_bf16(wgh[i][ks], bh, acc[i][j], 0, 0, 0);
            acc[i][j] = __builtin_amdgcn_mfma_f32_16x16x32_bf16(wgh[i][ks], bl, acc[i][j], 0, 0, 0);
            acc[i][j] = __builtin_amdgcn_mfma_f32_16x16x32_bf16(wgl[i][ks], bh, acc[i][j], 0, 0, 0);
          }
        }
      }
    }
  }

  // epilogue: bias, store h_pre, bn1 stats
#pragma unroll
  for (int i = 0; i < 2; ++i) {
    const int mt = wm * 2 + i;
#pragma unroll
    for (int r = 0; r < 4; ++r) {
      const int o = mt * 16 + q * 4 + r;
      const float bo = bsum[o];
      float sums = 0.f, sqs = 0.f;
#pragma unroll
      for (int j = 0; j < 7; ++j) {
        const int tile = wn * 7 + j;
        const int col = tile * 16 + l15;
        if (tile < 13 && col < 200 && t0 * 25 + col < TVN) {
          const float v = acc[i][j][r] + bo;
          hpre[(n * 64 + o) * TVN + t0 * 25 + col] = v;
          sums += v; sqs += v * v;
        }
      }
      sums += __shfl_xor(sums, 1); sqs += __shfl_xor(sqs, 1);
      sums += __shfl_xor(sums, 2); sqs += __shfl_xor(sqs, 2);
      sums += __shfl_xor(sums, 4); sqs += __shfl_xor(sqs, 4);
      sums += __shfl_xor(sums, 8); sqs += __shfl_xor(sqs, 8);
      if (l15 == 0) { ps[o * 2 + wn] = sums; pq[o * 2 + wn] = sqs; }
    }
  }
  __syncthreads();
  if (tid < 64) {
    atomicAdd(stat1 + tid, ps[tid * 2] + ps[tid * 2 + 1]);
    atomicAdd(stat1 + 64 + tid, pq[tid * 2] + pq[tid * 2 + 1]);
  }
}

__global__ __launch_bounds__(64) void k2_fin(
    const float* __restrict__ gamma, const float* __restrict__ beta,
    const float* __restrict__ stat, float* __restrict__ scsh) {
  const int o = threadIdx.x;
  double s = (double)stat[o], q = (double)stat[64 + o];
  double mean = s / (double)NTVf;
  double var = q / (double)NTVf - mean * mean;
  float sc = (float)((double)gamma[o] / sqrt(var + (double)EPSV));
  scsh[o] = sc;
  scsh[64 + o] = beta[o] - (float)mean * sc;
}

// K3 MFMA temporal conv (unchanged from passing R3 kernel)
__global__ __launch_bounds__(256) void k3_conv(
    const float* __restrict__ x, const float* __restrict__ hpre,
    const unsigned short* __restrict__ wAh, const unsigned short* __restrict__ wAl,
    const float* __restrict__ bt, const float* __restrict__ scsh1,
    float* __restrict__ out, float* __restrict__ stat2) {
  const int cb = blockIdx.x;          // 0..39
  const int n = blockIdx.y;
  const int tid = threadIdx.x;
  const int lane = tid & 63, w = tid >> 6;
  const int l15 = lane & 15, q = lane >> 4;
  const int kb8 = q * 8;
  const int outbase = cb * 192;

  __shared__ __align__(16) short smem[2 * 392 * 40];
  short* hh = smem;
  short* hl = smem + 392 * 40;

  f32x4 acc[4][3];
#pragma unroll
  for (int m = 0; m < 4; ++m)
#pragma unroll
    for (int nt = 0; nt < 3; ++nt) {
      f32x4 z = {0.f, 0.f, 0.f, 0.f};
      acc[m][nt] = z;
    }

  for (int ch = 0; ch < 2; ++ch) {
    __syncthreads();
    for (int u = tid; u < 3136; u += 256) {
      const int s = u % 392, cq = u / 392;
      const int gc = outbase - 100 + s;
      const int cbase = ch * 32 + cq * 4;
      short4 vh, vl;
      if (gc >= 0 && gc < TVN) {
#pragma unroll
        for (int i = 0; i < 4; ++i) {
          const int c = cbase + i;
          const float h = hpre[(n * 64 + c) * TVN + gc];
          const float xv = x[(n * 64 + c) * TVN + gc];
          const float r = fmaxf(fmaf(h, scsh1[c], scsh1[64 + c]) + xv, 0.f);
          const unsigned short hi = f2bf(r);
          ((unsigned short*)&vh)[i] = hi;
          ((unsigned short*)&vl)[i] = f2bf(r - bf2f(hi));
        }
      } else {
        vh.x = 0; vh.y = 0; vh.z = 0; vh.w = 0;
        vl.x = 0; vl.y = 0; vl.z = 0; vl.w = 0;
      }
      *(short4*)(hh + s * 40 + cq * 4) = vh;
      *(short4*)(hl + s * 40 + cq * 4) = vl;
    }
    __syncthreads();

#pragma unroll 3
    for (int kt = 0; kt < 9; ++kt) {
      short8v ah[4], al[4], bh[3], bl[3];
      const int abase = (kt * 2 + ch) * 2048;
#pragma unroll
      for (int m = 0; m < 4; ++m) {
        const int aoff = abase + (m * 16 + l15) * 32 + kb8;
        ah[m] = *(const short8v*)(wAh + aoff);
        al[m] = *(const short8v*)(wAl + aoff);
      }
#pragma unroll
      for (int nt = 0; nt < 3; ++nt) {
        const int s = w * 48 + nt * 16 + l15 + kt * 25;
        const int boff = s * 40 + kb8;
        bh[nt] = *(const short8v*)(hh + boff);
        bl[nt] = *(const short8v*)(hl + boff);
      }
#pragma unroll
      for (int m = 0; m < 4; ++m)
#pragma unroll
        for (int nt = 0; nt < 3; ++nt) {
          acc[m][nt] = __builtin_amdgcn_mfma_f32_16x16x32_bf16(ah[m], bh[nt], acc[m][nt], 0, 0, 0);
          acc[m][nt] = __builtin_amdgcn_mfma_f32_16x16x32_bf16(ah[m], bl[nt], acc[m][nt], 0, 0, 0);
          acc[m][nt] = __builtin_amdgcn_mfma_f32_16x16x32_bf16(al[m], bh[nt], acc[m][nt], 0, 0, 0);
        }
    }
  }

  __syncthreads();
  float* ps = (float*)smem;
  float* pq = ps + 64 * 65;
  const int g = w * 16 + l15;
#pragma unroll
  for (int m = 0; m < 4; ++m)
#pragma unroll
    for (int r = 0; r < 4; ++r) {
      const int o = m * 16 + q * 4 + r;
      const float bo = bt[o];
      float ssum = 0.f, ssq = 0.f;
#pragma unroll
      for (int nt = 0; nt < 3; ++nt) {
        const int col = outbase + (w * 3 + nt) * 16 + l15;
        if (col < TVN) {
          const float v = acc[m][nt][r] + bo;
          out[(n * 64 + o) * TVN + col] = v;
          ssum += v; ssq += v * v;
        }
      }
      ps[o * 65 + g] = ssum;
      pq[o * 65 + g] = ssq;
    }
  __syncthreads();
  if (tid < 64) {
    float s2 = 0.f, q2 = 0.f;
    for (int gg = 0; gg < 64; ++gg) { s2 += ps[tid * 65 + gg]; q2 += pq[tid * 65 + gg]; }
    atomicAdd(stat2 + tid, s2);
    atomicAdd(stat2 + 64 + tid, q2);
  }
}

__global__ __launch_bounds__(256) void k5_final(
    const float* __restrict__ x, const float* __restrict__ scsh2,
    float* __restrict__ out) {
  const int total = TOTE / 4;
  for (int ch = blockIdx.x * 256 + threadIdx.x; ch < total; ch += gridDim.x * 256) {
    const int f = ch * 4;
    const int o = (f / TVN) & 63;
    const float sc = scsh2[o], sh = scsh2[64 + o];
    float4 y4 = *(float4*)(out + f);
    const float4 x4 = *(const float4*)(x + f);
    y4.x = fmaxf(fmaf(y4.x, sc, sh) + x4.x, 0.f);
    y4.y = fmaxf(fmaf(y4.y, sc, sh) + x4.y, 0.f);
    y4.z = fmaxf(fmaf(y4.z, sc, sh) + x4.z, 0.f);
    y4.w = fmaxf(fmaf(y4.w, sc, sh) + x4.w, 0.f);
    *(float4*)(out + f) = y4;
  }
}

extern "C" void kernel_launch(void* const* d_in, const int* in_sizes, int n_in,
                              void* d_out, int out_size, void* d_ws, size_t ws_size,
                              hipStream_t stream) {
  const float* x      = (const float*)d_in[0];
  const float* A      = (const float*)d_in[1];
  const float* attn   = (const float*)d_in[2];
  const float* wg     = (const float*)d_in[3];
  const float* bg     = (const float*)d_in[4];
  const float* gamma1 = (const float*)d_in[5];
  const float* beta1  = (const float*)d_in[6];
  const float* wt     = (const float*)d_in[7];
  const float* bt     = (const float*)d_in[8];
  const float* gamma2 = (const float*)d_in[9];
  const float* beta2  = (const float*)d_in[10];
  float* ws = (float*)d_ws;
  float* out = (float*)d_out;
  const unsigned short* wAh  = (const unsigned short*)(ws + WTT_OFF);
  const unsigned short* wAl  = wAh + 36864;
  const unsigned short* AePh = (const unsigned short*)(ws + AEP_OFF);
  const unsigned short* AePl = AePh + 3072;
  const unsigned short* WgPh = (const unsigned short*)(ws + WGP_OFF);
  const unsigned short* WgPl = WgPh + 12288;

  k0_prep<<<64, 256, 0, stream>>>(A, attn, wg, bg, wt, ws);
  k1_gcn<<<dim3(38, 64), 256, 0, stream>>>(
      x, AePh, AePl, WgPh, WgPl, ws + BSUM_OFF, ws + HPRE_OFF, ws + STAT_OFF);
  k2_fin<<<1, 64, 0, stream>>>(gamma1, beta1, ws + STAT_OFF, ws + SCSH_OFF);
  k3_conv<<<dim3(40, 64), 256, 0, stream>>>(
      x, ws + HPRE_OFF, wAh, wAl, bt, ws + SCSH_OFF, out, ws + STAT_OFF + 128);
  k2_fin<<<1, 64, 0, stream>>>(gamma2, beta2, ws + STAT_OFF + 128, ws + SCSH_OFF + 128);
  k5_final<<<2048, 256, 0, stream>>>(x, ws + SCSH_OFF + 128, out);
}